// Round 9
// baseline (2427.634 us; speedup 1.0000x reference)
//
#include <hip/hip_runtime.h>
#include <hip/hip_bf16.h>

#define NPTS 200000
#define CIN 64
#define COUT 64
#define KVOL 27
#define NPAIRS 100000
#define NTOT (KVOL * NPAIRS)                                                     // 2.7M
#define NSUB 4                                                                   // sub-counters
#define GROUPS_PER_K (NPAIRS / 16)                                               // 6250
#define GROUPS_PER_BLOCK 64
#define CHUNKS_PER_K ((GROUPS_PER_K + GROUPS_PER_BLOCK - 1) / GROUPS_PER_BLOCK)  // 98
#define PAIR_BLOCKS ((NTOT + 255) / 256)                                         // 10547
#define SCAN_BLOCKS ((NPTS + 255) / 256)                                         // 782
#define RED_BLOCKS 4096
#define BN_EPS 1e-5f

typedef __attribute__((ext_vector_type(8))) short short8;   // 8 bf16 bits
typedef __attribute__((ext_vector_type(4))) float f32x4;

__device__ inline ushort f2bf(float x) {
    union { __hip_bfloat16 h; ushort u; } cv;
    cv.h = __float2bfloat16(x);   // RNE
    return cv.u;
}
__device__ inline float bf2f(ushort v) {
    union { unsigned u; float f; } cv; cv.u = ((unsigned)v) << 16; return cv.f;
}

// ---- Phase A: counting sort -> slot permutation pos[t] ---------------------

__global__ __launch_bounds__(256) void hist_kernel(
    const int* __restrict__ out_map, int* __restrict__ cnt4)
{
    const int t = blockIdx.x * 256 + threadIdx.x;
    if (t < NTOT)
        atomicAdd(&cnt4[out_map[t] * NSUB + (t & (NSUB - 1))], 1);
}

__global__ __launch_bounds__(256) void scan_block_kernel(
    const int* __restrict__ cnt4, int* __restrict__ row_off, int* __restrict__ bsum)
{
    __shared__ int s[256];
    const int tid = threadIdx.x;
    const int idx = blockIdx.x * 256 + tid;
    int v = 0;
    if (idx < NPTS) {
        #pragma unroll
        for (int j = 0; j < NSUB; ++j) v += cnt4[idx * NSUB + j];
    }
    s[tid] = v;
    __syncthreads();
    for (int d = 1; d < 256; d <<= 1) {
        const int t = (tid >= d) ? s[tid - d] : 0;
        __syncthreads();
        s[tid] += t;
        __syncthreads();
    }
    if (idx < NPTS) row_off[idx] = s[tid] - v;   // block-local exclusive
    if (tid == 255) bsum[blockIdx.x] = s[255];
}

__global__ __launch_bounds__(1024) void scan_bsum_kernel(int* __restrict__ bsum)
{
    __shared__ int s[1024];
    const int tid = threadIdx.x;
    const int v = (tid < SCAN_BLOCKS) ? bsum[tid] : 0;
    s[tid] = v;
    __syncthreads();
    for (int d = 1; d < 1024; d <<= 1) {
        const int t = (tid >= d) ? s[tid - d] : 0;
        __syncthreads();
        s[tid] += t;
        __syncthreads();
    }
    if (tid < SCAN_BLOCKS) bsum[tid] = s[tid] - v;  // exclusive
}

// Finalize row_off; convert cnt4 IN PLACE into running sub-cursors.
__global__ __launch_bounds__(256) void add_offsets_kernel(
    int* __restrict__ row_off, const int* __restrict__ bsum, int* __restrict__ cnt4)
{
    const int idx = blockIdx.x * 256 + threadIdx.x;
    if (idx < NPTS) {
        int o = row_off[idx] + bsum[blockIdx.x];
        row_off[idx] = o;
        #pragma unroll
        for (int j = 0; j < NSUB; ++j) {
            const int c = cnt4[idx * NSUB + j];
            cnt4[idx * NSUB + j] = o;   // becomes cursor
            o += c;
        }
    }
    if (idx == 0) row_off[NPTS] = NTOT;
}

// pos[t] = sorted slot of pair t. COALESCED write (the R8 fill scattered 174MB).
__global__ __launch_bounds__(256) void fill_kernel(
    const int* __restrict__ out_map, int* __restrict__ cur4, int* __restrict__ pos)
{
    const int t = blockIdx.x * 256 + threadIdx.x;
    if (t < NTOT) {
        const int slot = atomicAdd(&cur4[out_map[t] * NSUB + (t & (NSUB - 1))], 1);
        pos[t] = slot;
    }
}

// ---- Phase B: per-k gather+GEMM, contrib row written DIRECTLY to its sorted
// slot (random 128B full-row store, L2-merged, fire-and-forget) ---------------
// Swapped operands (HW-verified R5): lane (q,m) holds couts nt*16+q*4+[0..3]
// of pair m -> 4 x 8B stores into pair m's slot row.
__global__ __launch_bounds__(256) void contrib_gemm_kernel(
    const float* __restrict__ feats,      // fp32 [NPTS][CIN]
    const float* __restrict__ wk,         // fp32 [KVOL][CIN][COUT]
    const int* __restrict__ in_map,       // [KVOL][NPAIRS]
    const int* __restrict__ pos,          // [NTOT] sorted slot of pair t
    ushort* __restrict__ contrib)         // bf16 [NTOT][COUT], sorted by out row
{
    const int koff  = blockIdx.x / CHUNKS_PER_K;
    const int chunk = blockIdx.x % CHUNKS_PER_K;
    const int lane  = threadIdx.x & 63;
    const int wave  = threadIdx.x >> 6;
    const int m     = lane & 15;
    const int q     = lane >> 4;

    short8 wfrag[2][4];
    const float* wbase = wk + koff * (CIN * COUT);
    #pragma unroll
    for (int h = 0; h < 2; ++h)
        #pragma unroll
        for (int nt = 0; nt < 4; ++nt)
            #pragma unroll
            for (int e = 0; e < 8; ++e) {
                const int kin = h * 32 + q * 8 + e;
                wfrag[h][nt][e] = (short)f2bf(wbase[kin * COUT + nt * 16 + m]);
            }

    const int* imap = in_map + koff * NPAIRS;
    const int* kpos = pos + koff * NPAIRS;

    #pragma unroll 1
    for (int it = 0; it < GROUPS_PER_BLOCK / 4; ++it) {
        const int g = chunk * GROUPS_PER_BLOCK + it * 4 + wave;
        if (g >= GROUPS_PER_K) break;
        const int base = g * 16;

        const int row  = imap[base + m];
        const int slot = kpos[base + m];

        const float* fr = feats + (size_t)row * CIN + q * 8;
        const f32x4 f00 = *(const f32x4*)(fr);
        const f32x4 f01 = *(const f32x4*)(fr + 4);
        const f32x4 f10 = *(const f32x4*)(fr + 32);
        const f32x4 f11 = *(const f32x4*)(fr + 36);

        short8 b0, b1;
        #pragma unroll
        for (int e = 0; e < 4; ++e) {
            b0[e]     = (short)f2bf(f00[e]);
            b0[e + 4] = (short)f2bf(f01[e]);
            b1[e]     = (short)f2bf(f10[e]);
            b1[e + 4] = (short)f2bf(f11[e]);
        }

        f32x4 acc[4];
        #pragma unroll
        for (int nt = 0; nt < 4; ++nt) acc[nt] = (f32x4){0.f, 0.f, 0.f, 0.f};
        #pragma unroll
        for (int nt = 0; nt < 4; ++nt) {
            acc[nt] = __builtin_amdgcn_mfma_f32_16x16x32_bf16(wfrag[0][nt], b0, acc[nt], 0, 0, 0);
            acc[nt] = __builtin_amdgcn_mfma_f32_16x16x32_bf16(wfrag[1][nt], b1, acc[nt], 0, 0, 0);
        }

        ushort* crow = contrib + ((size_t)slot << 6) + q * 4;
        #pragma unroll
        for (int nt = 0; nt < 4; ++nt) {
            ushort4 st;
            st.x = f2bf(acc[nt][0]); st.y = f2bf(acc[nt][1]);
            st.z = f2bf(acc[nt][2]); st.w = f2bf(acc[nt][3]);
            *(ushort4*)(crow + nt * 16) = st;
        }
    }
}

// ---- Phase C: sequential per-row reduce + fused BN/ReLU --------------------
// One wave per out row, lane = cout. Contrib rows for this out row are
// CONTIGUOUS [s,e) -> streaming 128B reads, 8 in flight.
__global__ __launch_bounds__(256) void reduce_kernel(
    const ushort* __restrict__ contrib,   // bf16 [NTOT][COUT] sorted
    const int* __restrict__ row_off,      // [NPTS+1]
    const float* __restrict__ gamma, const float* __restrict__ beta,
    const float* __restrict__ rmean, const float* __restrict__ rvar,
    float* __restrict__ out)
{
    const int lane = threadIdx.x & 63;
    const int wid  = blockIdx.x * 4 + (threadIdx.x >> 6);

    const float sc = gamma[lane] * rsqrtf(rvar[lane] + BN_EPS);
    const float bi = beta[lane] - rmean[lane] * sc;

    #pragma unroll 1
    for (int row = wid; row < NPTS; row += RED_BLOCKS * 4) {
        const int s = row_off[row];
        const int n = row_off[row + 1] - s;
        const ushort* base = contrib + ((size_t)s << 6) + lane;

        float a = 0.f;
        int i = 0;
        for (; i + 8 <= n; i += 8) {
            const ushort v0 = base[(size_t)(i + 0) << 6];
            const ushort v1 = base[(size_t)(i + 1) << 6];
            const ushort v2 = base[(size_t)(i + 2) << 6];
            const ushort v3 = base[(size_t)(i + 3) << 6];
            const ushort v4 = base[(size_t)(i + 4) << 6];
            const ushort v5 = base[(size_t)(i + 5) << 6];
            const ushort v6 = base[(size_t)(i + 6) << 6];
            const ushort v7 = base[(size_t)(i + 7) << 6];
            a += bf2f(v0) + bf2f(v1) + bf2f(v2) + bf2f(v3)
               + bf2f(v4) + bf2f(v5) + bf2f(v6) + bf2f(v7);
        }
        for (; i < n; ++i) a += bf2f(base[(size_t)i << 6]);

        out[(size_t)row * COUT + lane] = fmaxf(a * sc + bi, 0.f);
    }
}

// ---- Fallback (tiny workspace): proven R4 flat-scatter path ----------------
__global__ __launch_bounds__(256) void fb_conv_scatter(
    const float* __restrict__ feats, const float* __restrict__ wk,
    const int* __restrict__ in_map, const int* __restrict__ out_map,
    float* __restrict__ accum)
{
    const int koff  = blockIdx.x / CHUNKS_PER_K;
    const int chunk = blockIdx.x % CHUNKS_PER_K;
    const int lane  = threadIdx.x & 63;
    const int wave  = threadIdx.x >> 6;
    const int m = lane & 15, q = lane >> 4;
    short8 wfrag[2][4];
    const float* wbase = wk + koff * (CIN * COUT);
    #pragma unroll
    for (int h = 0; h < 2; ++h)
        #pragma unroll
        for (int nt = 0; nt < 4; ++nt)
            #pragma unroll
            for (int e = 0; e < 8; ++e)
                wfrag[h][nt][e] = (short)f2bf(wbase[(h*32 + q*8 + e) * COUT + nt*16 + m]);
    const int* imap = in_map + koff * NPAIRS;
    const int* omap = out_map + koff * NPAIRS;
    #pragma unroll 1
    for (int it = 0; it < GROUPS_PER_BLOCK / 4; ++it) {
        const int g = chunk * GROUPS_PER_BLOCK + it * 4 + wave;
        if (g >= GROUPS_PER_K) break;
        const int base = g * 16;
        const int row = imap[base + m];
        const float* fr = feats + (size_t)row * CIN + q * 8;
        const f32x4 f00 = *(const f32x4*)(fr);
        const f32x4 f01 = *(const f32x4*)(fr + 4);
        const f32x4 f10 = *(const f32x4*)(fr + 32);
        const f32x4 f11 = *(const f32x4*)(fr + 36);
        short8 b0, b1;
        #pragma unroll
        for (int e = 0; e < 4; ++e) {
            b0[e] = (short)f2bf(f00[e]); b0[e+4] = (short)f2bf(f01[e]);
            b1[e] = (short)f2bf(f10[e]); b1[e+4] = (short)f2bf(f11[e]);
        }
        f32x4 acc[4];
        #pragma unroll
        for (int nt = 0; nt < 4; ++nt) acc[nt] = (f32x4){0.f,0.f,0.f,0.f};
        #pragma unroll
        for (int nt = 0; nt < 4; ++nt) {
            acc[nt] = __builtin_amdgcn_mfma_f32_16x16x32_bf16(wfrag[0][nt], b0, acc[nt], 0,0,0);
            acc[nt] = __builtin_amdgcn_mfma_f32_16x16x32_bf16(wfrag[1][nt], b1, acc[nt], 0,0,0);
        }
        const int orow = omap[base + m];
        float* obase = accum + (size_t)orow * COUT + q * 4;
        #pragma unroll
        for (int nt = 0; nt < 4; ++nt)
            #pragma unroll
            for (int r = 0; r < 4; ++r)
                atomicAdd(obase + nt * 16 + r, acc[nt][r]);
    }
}

__global__ __launch_bounds__(256) void fb_bn_relu(
    const float* __restrict__ accum,
    const float* __restrict__ gamma, const float* __restrict__ beta,
    const float* __restrict__ rmean, const float* __restrict__ rvar,
    float* __restrict__ out)
{
    const int idx = (blockIdx.x * 256 + threadIdx.x) * 4;
    if (idx < NPTS * COUT) {
        const f32x4 v = *(const f32x4*)(accum + idx);
        const int c0 = idx & (COUT - 1);
        f32x4 o;
        #pragma unroll
        for (int e = 0; e < 4; ++e) {
            const float sc = gamma[c0+e] * rsqrtf(rvar[c0+e] + BN_EPS);
            o[e] = fmaxf(v[e] * sc + (beta[c0+e] - rmean[c0+e] * sc), 0.f);
        }
        *(f32x4*)(out + idx) = o;
    }
}

// ---- launch -----------------------------------------------------------------
extern "C" void kernel_launch(void* const* d_in, const int* in_sizes, int n_in,
                              void* d_out, int out_size, void* d_ws, size_t ws_size,
                              hipStream_t stream) {
    const float* feats = (const float*)d_in[0];
    const float* wk    = (const float*)d_in[1];
    const float* gamma = (const float*)d_in[2];
    const float* beta  = (const float*)d_in[3];
    const float* rmean = (const float*)d_in[4];
    const float* rvar  = (const float*)d_in[5];
    const int* imap    = (const int*)d_in[6];
    const int* omap    = (const int*)d_in[7];
    float* out         = (float*)d_out;

    char* ws = (char*)d_ws;
    auto al = [](size_t x) { return (x + 1023) & ~(size_t)1023; };

    size_t p = 0;
    int* cnt4     = (int*)(ws + p); p += al((size_t)NPTS * NSUB * 4);   // 3.2 MB (hist -> cursors)
    int* row_off  = (int*)(ws + p); p += al(((size_t)NPTS + 1) * 4);    // 0.8 MB
    int* bsum     = (int*)(ws + p); p += al(1024 * 4);
    int* pos      = (int*)(ws + p); p += al((size_t)NTOT * 4);          // 10.8 MB
    ushort* contrib = (ushort*)(ws + p); p += al((size_t)NTOT * COUT * 2); // 345.6 MB

    if (ws_size < p) {
        // Fallback: proven flat-scatter (atomic-rate bound, 675 us, correct).
        float* accum = (float*)d_ws;
        hipMemsetAsync(accum, 0, (size_t)NPTS * COUT * 4, stream);
        fb_conv_scatter<<<KVOL * CHUNKS_PER_K, 256, 0, stream>>>(feats, wk, imap, omap, accum);
        fb_bn_relu<<<(NPTS * COUT / 4 + 255) / 256, 256, 0, stream>>>(
            accum, gamma, beta, rmean, rvar, out);
        return;
    }

    hipMemsetAsync(cnt4, 0, (size_t)NPTS * NSUB * 4, stream);
    hist_kernel<<<PAIR_BLOCKS, 256, 0, stream>>>(omap, cnt4);
    scan_block_kernel<<<SCAN_BLOCKS, 256, 0, stream>>>(cnt4, row_off, bsum);
    scan_bsum_kernel<<<1, 1024, 0, stream>>>(bsum);
    add_offsets_kernel<<<SCAN_BLOCKS, 256, 0, stream>>>(row_off, bsum, cnt4);
    fill_kernel<<<PAIR_BLOCKS, 256, 0, stream>>>(omap, cnt4, pos);

    contrib_gemm_kernel<<<KVOL * CHUNKS_PER_K, 256, 0, stream>>>(
        feats, wk, imap, pos, contrib);

    reduce_kernel<<<RED_BLOCKS, 256, 0, stream>>>(
        contrib, row_off, gamma, beta, rmean, rvar, out);
}